// Round 5
// baseline (534.930 us; speedup 1.0000x reference)
//
#include <hip/hip_runtime.h>

// LogicVAE: graph-GRU VAE encoder. B=2048,N=32,V=10,H=256,Z=64.
// gm[b,n] = sigmoid(h@w_gate+b_gate)*(h@w_map) is a pure function of the FINAL
// hidden[b,n] (adj strictly upper-tri), so it's computed once per node.
// R10 = R8 + amdgpu_waves_per_eu(4,4). Diagnosis chain:
//  - WRITE ~80-90MiB every round = 320 B/thread scratch spill, re-read each
//    step; per-XCD scratch stream (10MB > 4MB L2) evicts the 640KB weight
//    working set -> the 1.2GB FETCH and the dur==bytes/2.8TB/s wall.
//  - VGPR_Count=64 with launch_bounds(1024,4): the allocator's occupancy
//    heuristic aimed at 8 waves/EU (ignoring that 154KB LDS forces 1 blk/CU
//    = 4 waves/EU max), capped regs at 64, and spilled. waves_per_eu(4,4)
//    pins the target -> full 128-reg budget, kernel needs ~100 -> no spill.
//  - R9's asm-pinned wG/wM dropped (64 regs won't fit 128 budget); phase D
//    streams wgm from L2, which should now stay resident.
// LDS: 131072+8448+8448+1024+1024+3072+1024 = 154112 B (1 blk/CU, 16 waves).

#define BB 2048
#define NN 32
#define VV 10
#define HH 256
#define ZZ 64
#define BT 8      // batches per block
#define KC 8      // K chunks: 256/32
#define NT1 48    // 768/16 col tiles (w_hh)
#define NT2 32    // 512/16 col tiles (w_gate||w_map)
#define WHH_ELEMS (NT1 * KC * 64 * 8)             // 196608 ushorts (384 KB)
#define WGM_ELEMS (NT2 * KC * 64 * 8)             // 131072 ushorts (256 KB)

typedef __attribute__((ext_vector_type(8))) short frag8;            // 8 bf16 (4 VGPR)
typedef __attribute__((ext_vector_type(4))) float facc4;            // MFMA accum
typedef __attribute__((ext_vector_type(4))) unsigned short us4;     // 8B LDS load

__device__ __forceinline__ float bf2f(unsigned short u) {
    unsigned int x = ((unsigned int)u) << 16;
    return __builtin_bit_cast(float, x);
}
__device__ __forceinline__ unsigned short f2bf(float f) {
    unsigned int x = __builtin_bit_cast(unsigned int, f);
    x += 0x7FFFu + ((x >> 16) & 1u);
    return (unsigned short)(x >> 16);
}
__device__ __forceinline__ float sigm(float x) { return 1.0f / (1.0f + __expf(-x)); }
__device__ __forceinline__ float ldv(const float* p, size_t i) { return p[i]; }
__device__ __forceinline__ float ldv(const unsigned short* p, size_t i) { return bf2f(p[i]); }
__device__ __forceinline__ void stv(float* p, size_t i, float v) { p[i] = v; }
__device__ __forceinline__ void stv(unsigned short* p, size_t i, float v) { p[i] = f2bf(v); }

// flag=1 => buffers are fp32, flag=0 => bf16. Integer-only tests (fast-math safe).
__global__ void detect_dtype(const unsigned short* __restrict__ w, int* flag) {
    __shared__ int zc, bc;
    if (threadIdx.x == 0) { zc = 0; bc = 0; }
    __syncthreads();
    int z = 0, b = 0;
    for (int i = threadIdx.x; i < 2048; i += 256) {
        unsigned short lo = w[2 * i];            // fp32: low mantissa half / bf16: a value
        if (lo == 0) z++;                        // bf16-rounded fp32 storage => all zero
        unsigned e = (lo >> 7) & 0xFFu;          // bf16 exponent field
        if (e >= 0x86u) b++;                     // |x|>=128 or NaN: impossible for N(0,.05) bf16
    }
    atomicAdd(&zc, z); atomicAdd(&bc, b);
    __syncthreads();
    if (threadIdx.x == 0) *flag = (bc > 0 || zc > 512) ? 1 : 0;
}

// Repack w_hh (256x768) and w_gate||w_map (256x512) into bf16 MFMA B-fragment
// order: frag f=jt*KC+kc; elem[(f*64+lane)*8+j] = W[kc*32+(lane>>4)*8+j][jt*16+(lane&15)]
// Tail threads build wihG[10][768] = fp32(w_ih + b_ih) folded table.
template <typename T>
__global__ void repack_weights(const T* __restrict__ w_hh,
                               const T* __restrict__ w_gate,
                               const T* __restrict__ w_map,
                               const T* __restrict__ w_ih,
                               const T* __restrict__ b_ih,
                               unsigned short* __restrict__ whh_p,
                               unsigned short* __restrict__ wgm_p,
                               float* __restrict__ wihG,
                               const int* __restrict__ flag, int want) {
    if (*flag != want) return;
    int t = blockIdx.x * blockDim.x + threadIdx.x;
    int lane = t & 63;
    int frag = t >> 6;                  // 0..759
    int kbase = (lane >> 4) * 8;
    if (frag < NT1 * KC) {
        int jt = frag / KC, kc = frag % KC;
        int col = jt * 16 + (lane & 15);
        unsigned short* dst = whh_p + ((size_t)frag * 64 + lane) * 8;
        #pragma unroll
        for (int j = 0; j < 8; ++j)
            dst[j] = f2bf(ldv(w_hh, (size_t)(kc * 32 + kbase + j) * 768 + col));
    } else if (frag < (NT1 + NT2) * KC) {
        int f2 = frag - NT1 * KC;
        int jt = f2 / KC, kc = f2 % KC;
        int col = jt * 16 + (lane & 15);
        unsigned short* dst = wgm_p + ((size_t)f2 * 64 + lane) * 8;
        #pragma unroll
        for (int j = 0; j < 8; ++j) {
            int k = kc * 32 + kbase + j;
            dst[j] = f2bf((col < HH) ? ldv(w_gate, (size_t)k * HH + col)
                                     : ldv(w_map, (size_t)k * HH + (col - HH)));
        }
    } else {
        int idx = t - (NT1 + NT2) * KC * 64;     // 0..7679 with grid=190
        if (idx < VV * 768) {
            int c = idx % 768;
            wihG[idx] = ldv(w_ih, (size_t)idx) + ldv(b_ih, (size_t)c);
        }
    }
}

template <typename T>
__global__ __launch_bounds__(1024)
__attribute__((amdgpu_waves_per_eu(4, 4)))   // LDS forces 1 blk/CU = 4 waves/EU;
void vae_main(                               // pin it so allocator uses 128 regs
    const T* __restrict__ adj,
    const int* __restrict__ ntypes,
    const T* __restrict__ b_hh,
    const T* __restrict__ b_gate,
    const T* __restrict__ w_mu,
    const T* __restrict__ b_mu,
    const T* __restrict__ w_std,
    const T* __restrict__ b_std,
    const unsigned short* __restrict__ whh_p,
    const unsigned short* __restrict__ wgm_p,
    const float* __restrict__ wihG,
    T* __restrict__ out,
    const int* __restrict__ flag, int want)
{
    if (*flag != want) return;

    __shared__ __align__(16) unsigned short gmAll[BT][NN][HH]; // gm state (128 KB)
    __shared__ __align__(16) unsigned short aggbf[16][264];    // MFMA A src rows 0..7
    __shared__ __align__(16) unsigned short hnew[16][264];     // MFMA A src rows 0..7
    __shared__ unsigned int  amask[BT][NN];                    // adj bitmasks (1 KB)
    __shared__ int           ntva[BT][NN];                     // node types (1 KB)
    __shared__ __align__(16) float bhhL[768];                  // b_hh (3 KB)
    __shared__ float bgL[HH];                                  // b_gate (1 KB)

    // fp32 agg overlays the dead rows 8..15 (those MFMA C-rows are discarded;
    // garbage A-rows 8..15 only pollute discarded C-rows 8..15).
    float* const aggA = (float*)&aggbf[8][0];   // bi 0..3: 4x256 fp32 (4 KB)
    float* const aggB = (float*)&hnew[8][0];    // bi 4..7

    const int tid  = threadIdx.x;
    const int lane = tid & 63;
    const int w    = tid >> 6;          // wave 0..15
    const int b0   = blockIdx.x * BT;

    const frag8* whh8 = (const frag8*)whh_p;
    const frag8* wgm8 = (const frag8*)wgm_p;

    // ---- one-time preload ----
    if (tid < 256) {                         // adj -> bitmask (adj is exactly {0,1})
        int bi = tid >> 5, vv = tid & 31;
        unsigned m = 0;
        for (int n = 0; n < NN; ++n)
            if (ldv(adj, ((size_t)(b0 + bi) * NN + n) * NN + vv) != 0.0f) m |= (1u << n);
        amask[bi][vv] = m;
    } else if (tid < 512) {
        int idx = tid - 256;
        int bi = idx >> 5, vv = idx & 31;
        ntva[bi][vv] = ntypes[(b0 + bi) * NN + vv];
    }
    for (int i = tid; i < 768; i += 1024) bhhL[i] = ldv(b_hh, i);
    if (tid < HH) bgL[tid] = ldv(b_gate, tid);
    __syncthreads();

    for (int v = 0; v < NN; ++v) {
        // ---- A (waves 0..7): agg over neighbor gm rows, all from LDS.
        if (w < BT) {
            const int bi = w;
            const int h4 = lane * 4;
            unsigned m = amask[bi][v];       // wave-uniform
            float a0 = 0.f, a1 = 0.f, a2 = 0.f, a3 = 0.f;
            const unsigned short* rb = &gmAll[bi][0][0] + h4;
            while (m) {                      // 2-wide to keep 2 ds_reads in flight
                const int n0 = __builtin_ctz(m); m &= m - 1;
                const us4 g0 = *(const us4*)(rb + n0 * HH);
                if (m) {
                    const int n1 = __builtin_ctz(m); m &= m - 1;
                    const us4 g1 = *(const us4*)(rb + n1 * HH);
                    a0 += bf2f(g0.x) + bf2f(g1.x);
                    a1 += bf2f(g0.y) + bf2f(g1.y);
                    a2 += bf2f(g0.z) + bf2f(g1.z);
                    a3 += bf2f(g0.w) + bf2f(g1.w);
                } else {
                    a0 += bf2f(g0.x); a1 += bf2f(g0.y);
                    a2 += bf2f(g0.z); a3 += bf2f(g0.w);
                }
            }
            float* ap = (bi < 4) ? (aggA + bi * 256) : (aggB + (bi - 4) * 256);
            *(float4*)(ap + h4) = make_float4(a0, a1, a2, a3);
            ushort4 ab; ab.x = f2bf(a0); ab.y = f2bf(a1); ab.z = f2bf(a2); ab.w = f2bf(a3);
            *(ushort4*)&aggbf[bi][h4] = ab;
        }
        __syncthreads();

        // ---- B: gh = agg @ w_hh (MFMA) fused with GRU elementwise -> hnew
        {
            const int t = w;                             // triplet: cols t, t+16, t+32
            const int col = t * 16 + (lane & 15);
            const int q = lane >> 4;                     // C row = 4q+i, valid q<2

            facc4 aR = {0.f, 0.f, 0.f, 0.f};
            facc4 aZ = {0.f, 0.f, 0.f, 0.f};
            facc4 aN = {0.f, 0.f, 0.f, 0.f};
            const frag8* pR = whh8 + (size_t)(t     ) * (KC * 64) + lane;
            const frag8* pZ = whh8 + (size_t)(t + 16) * (KC * 64) + lane;
            const frag8* pN = whh8 + (size_t)(t + 32) * (KC * 64) + lane;
            #pragma unroll
            for (int kc = 0; kc < KC; ++kc) {            // per-kc afrag: 4 regs live
                const frag8 af = *(const frag8*)&aggbf[lane & 15][kc * 32 + (lane >> 4) * 8];
                aR = __builtin_amdgcn_mfma_f32_16x16x32_bf16(af, pR[kc * 64], aR, 0, 0, 0);
                aZ = __builtin_amdgcn_mfma_f32_16x16x32_bf16(af, pZ[kc * 64], aZ, 0, 0, 0);
                aN = __builtin_amdgcn_mfma_f32_16x16x32_bf16(af, pN[kc * 64], aN, 0, 0, 0);
            }
            if (q < 2) {
                const float bhr = bhhL[col], bhz = bhhL[col + 256], bhn = bhhL[col + 512];
                const float* ap = (q == 0) ? aggA : aggB;
                #pragma unroll
                for (int i = 0; i < 4; ++i) {
                    const float* wr = wihG + (size_t)ntva[4 * q + i][v] * 768 + col;
                    const float r = sigm(wr[0]   + aR[i] + bhr);
                    const float z = sigm(wr[256] + aZ[i] + bhz);
                    const float n = tanhf(wr[512] + r * (aN[i] + bhn));
                    hnew[4 * q + i][col] = f2bf((1.f - z) * n + z * ap[i * 256 + col]);
                }
            }
        }
        __syncthreads();

        // ---- D: gm_v = sigmoid(h@w_gate+b_gate) * (h@w_map) -> gmAll[.][v]
        //      (streams wgm from L2; pins don't fit the honest 128-reg budget)
        {
            facc4 aG = {0.f, 0.f, 0.f, 0.f};
            facc4 aM = {0.f, 0.f, 0.f, 0.f};
            const frag8* pG = wgm8 + (size_t)(w     ) * (KC * 64) + lane;
            const frag8* pM = wgm8 + (size_t)(w + 16) * (KC * 64) + lane;
            #pragma unroll
            for (int kc = 0; kc < KC; ++kc) {            // per-kc hfrag: 4 regs live
                const frag8 hf = *(const frag8*)&hnew[lane & 15][kc * 32 + (lane >> 4) * 8];
                aG = __builtin_amdgcn_mfma_f32_16x16x32_bf16(hf, pG[kc * 64], aG, 0, 0, 0);
                aM = __builtin_amdgcn_mfma_f32_16x16x32_bf16(hf, pM[kc * 64], aM, 0, 0, 0);
            }
            const int col = w * 16 + (lane & 15);        // 0..255
            const int q = lane >> 4;
            if (q < 2) {
                const float bg = bgL[col];
                #pragma unroll
                for (int i = 0; i < 4; ++i)
                    gmAll[4 * q + i][v][col] = f2bf(sigm(aG[i] + bg) * aM[i]);
            }
        }
        __syncthreads();   // gmAll row v / hnew ready for next step's A / epilogue
    }

    // ---- Epilogue: hg = h_new(v=31) (in hnew LDS); mu/sigma = hg@w_mu/std + b
    {
        const int bi = w >> 1, half = w & 1, z = lane;   // 2 waves per batch
        float am = 0.f, as = 0.f;
        const int h0 = half * 128;
        #pragma unroll 4
        for (int h = h0; h < h0 + 128; ++h) {
            const float hv = bf2f(hnew[bi][h]);          // LDS broadcast
            am += hv * ldv(w_mu, (size_t)h * ZZ + z);
            as += hv * ldv(w_std, (size_t)h * ZZ + z);
        }
        float* sc = (bi < 4) ? (aggA + bi * 256) : (aggB + (bi - 4) * 256);
        sc[half * 64 + z]       = am;                    // overlay region as scratch
        sc[128 + half * 64 + z] = as;
    }
    __syncthreads();
    if (w < BT) {
        const int bi = w, z = lane;
        const float* sc = (bi < 4) ? (aggA + bi * 256) : (aggB + (bi - 4) * 256);
        const float am = sc[z] + sc[64 + z] + ldv(b_mu, z);
        const float as = sc[128 + z] + sc[192 + z] + ldv(b_std, z);
        stv(out, (size_t)(b0 + bi) * ZZ + z, am);
        stv(out, (size_t)BB * ZZ + (size_t)(b0 + bi) * ZZ + z, as);
    }
}

extern "C" void kernel_launch(void* const* d_in, const int* in_sizes, int n_in,
                              void* d_out, int out_size, void* d_ws, size_t ws_size,
                              hipStream_t stream)
{
    unsigned short* whh_p = (unsigned short*)d_ws;
    unsigned short* wgm_p = whh_p + WHH_ELEMS;
    float* wihG = (float*)(wgm_p + WGM_ELEMS);             // byte off 655360 (16B aligned)

    // dtype flag lives in the last aligned 4 bytes of ws
    size_t flag_off = (ws_size >= 8) ? ((ws_size - 4) & ~(size_t)3) : 0;
    int* flag = (int*)((char*)d_ws + flag_off);

    detect_dtype<<<dim3(1), 256, 0, stream>>>((const unsigned short*)d_in[2], flag);

    // 190 blocks = 640 weight frags * 64 lanes + 7680 wihG elems, exactly
    repack_weights<float><<<dim3(190), 256, 0, stream>>>(
        (const float*)d_in[3], (const float*)d_in[6], (const float*)d_in[8],
        (const float*)d_in[2], (const float*)d_in[4],
        whh_p, wgm_p, wihG, flag, 1);
    repack_weights<unsigned short><<<dim3(190), 256, 0, stream>>>(
        (const unsigned short*)d_in[3], (const unsigned short*)d_in[6],
        (const unsigned short*)d_in[8], (const unsigned short*)d_in[2],
        (const unsigned short*)d_in[4],
        whh_p, wgm_p, wihG, flag, 0);

    vae_main<float><<<dim3(BB / BT), 1024, 0, stream>>>(
        (const float*)d_in[0], (const int*)d_in[1],
        (const float*)d_in[5], (const float*)d_in[7],
        (const float*)d_in[9], (const float*)d_in[10],
        (const float*)d_in[11], (const float*)d_in[12],
        whh_p, wgm_p, wihG, (float*)d_out, flag, 1);
    vae_main<unsigned short><<<dim3(BB / BT), 1024, 0, stream>>>(
        (const unsigned short*)d_in[0], (const int*)d_in[1],
        (const unsigned short*)d_in[5], (const unsigned short*)d_in[7],
        (const unsigned short*)d_in[9], (const unsigned short*)d_in[10],
        (const unsigned short*)d_in[11], (const unsigned short*)d_in[12],
        whh_p, wgm_p, wihG, (unsigned short*)d_out, flag, 0);
}